// Round 14
// baseline (410.590 us; speedup 1.0000x reference)
//
#include <hip/hip_runtime.h>

typedef __bf16 bf16;
typedef bf16 bf16x8 __attribute__((ext_vector_type(8)));
typedef bf16 bf16x4 __attribute__((ext_vector_type(4)));
typedef float f32x4 __attribute__((ext_vector_type(4)));

#define NB 16
#define CLL 64
#define CHH 192
#define NPIX 16384
#define SL (CLL * CLL)
#define SH (CHH * CHH)

// ---------------- DWT: img(f32) -> X_ll, X_hh (bf16) + channel sums; also zeroes G ----------
// 1024 blocks, one per (b,c); 8 row-slabs per block; block-reduced sums (no atomics, no memset).
__global__ __launch_bounds__(256) void k_dwt(const float* __restrict__ img, bf16* __restrict__ xll,
                      bf16* __restrict__ xhh, float* __restrict__ sll, float* __restrict__ shh,
                      float* __restrict__ Gll, float* __restrict__ Ghh) {
    __shared__ float sred[4][4];
    int bc = blockIdx.x;           // b*64 + c
    int b = bc >> 6, c = bc & 63;
    int t = threadIdx.x;
    int q = t & 15;                        // 8-px col group
    // zero G slices (consumed by k_gramv next kernel; replay-safe)
    {
        float4 z4 = make_float4(0.f, 0.f, 0.f, 0.f);
        int gi = bc * 256 + t;
        if (gi < 16384)  ((float4*)Gll)[gi] = z4;    // 16384 float4 = NB*SL floats
        if (gi < 147456) ((float4*)Ghh)[gi] = z4;    // 147456 float4 = NB*SH floats
    }
    float s0 = 0.f, s1 = 0.f, s2 = 0.f, s3 = 0.f;
    for (int it = 0; it < 8; it++) {
        int r = it * 16 + (t >> 4);        // out row 0..127
        const float* p0 = img + ((size_t)bc << 16) + (size_t)(2 * r) * 256 + 16 * q;
        const float* p1 = p0 + 256;
        float4 e0[4], e1[4];
        #pragma unroll
        for (int l = 0; l < 4; l++) { e0[l] = ((const float4*)p0)[l]; e1[l] = ((const float4*)p1)[l]; }
        const float* f0 = (const float*)e0;
        const float* f1 = (const float*)e1;
        bf16x8 vll, v1, v2, v3;
        #pragma unroll
        for (int p = 0; p < 8; p++) {
            float a = f0[2 * p], bb = f0[2 * p + 1], cc = f1[2 * p], d = f1[2 * p + 1];
            float wll = (a + bb + cc + d) * 0.5f;
            float w1  = (a - bb + cc - d) * 0.5f;
            float w2  = (a + bb - cc - d) * 0.5f;
            float w3  = (a - bb - cc + d) * 0.5f;
            vll[p] = (bf16)wll; v1[p] = (bf16)w1; v2[p] = (bf16)w2; v3[p] = (bf16)w3;
            s0 += wll; s1 += w1; s2 += w2; s3 += w3;
        }
        size_t n = (size_t)r * 128 + 8 * q;
        *(bf16x8*)(xll + ((size_t)b * CLL + c) * NPIX + n) = vll;
        size_t hb = ((size_t)b * CHH + 3 * c) * NPIX + n;
        *(bf16x8*)(xhh + hb) = v1;
        *(bf16x8*)(xhh + hb + NPIX) = v2;
        *(bf16x8*)(xhh + hb + 2 * NPIX) = v3;
    }
    for (int o = 32; o; o >>= 1) {
        s0 += __shfl_down(s0, o); s1 += __shfl_down(s1, o);
        s2 += __shfl_down(s2, o); s3 += __shfl_down(s3, o);
    }
    int wv = t >> 6;
    if ((t & 63) == 0) {
        sred[wv][0] = s0; sred[wv][1] = s1; sred[wv][2] = s2; sred[wv][3] = s3;
    }
    __syncthreads();
    if (t == 0) {
        float r0 = sred[0][0] + sred[1][0] + sred[2][0] + sred[3][0];
        float r1 = sred[0][1] + sred[1][1] + sred[2][1] + sred[3][1];
        float r2 = sred[0][2] + sred[1][2] + sred[2][2] + sred[3][2];
        float r3 = sred[0][3] + sred[1][3] + sred[2][3] + sred[3][3];
        sll[b * CLL + c] = r0;
        shh[b * CHH + 3 * c + 0] = r1;
        shh[b * CHH + 3 * c + 1] = r2;
        shh[b * CHH + 3 * c + 2] = r3;
    }
}

// ---------------- gramv: full-tile gram (hh 9 tiles, ll 1 tile) + vw^T transpose tail -------
// blocks 0..1151: hh (b x 9 tiles x 8 splitk); 1152..1407: ll (b x 16 splitk); 1408..1439: tail.
__global__ __launch_bounds__(256) void k_gramv(const bf16* __restrict__ xll,
        const bf16* __restrict__ xhh, float* __restrict__ Gll, float* __restrict__ Ghh,
        const float* __restrict__ llvw, const float* __restrict__ hvw,
        float* __restrict__ vwTll, float* __restrict__ vwThh) {
    __shared__ bf16 sA[64 * 64];
    __shared__ bf16 sB[64 * 64];
    int blk = blockIdx.x, t = threadIdx.x;
    if (blk >= 1408) {                       // vw^T transpose tail
        int base = (blk - 1408) * 256 + t;
        for (int idx = base; idx < SL + SH; idx += 32 * 256) {
            if (idx < SL) {
                int r = idx / CLL, k = idx % CLL;
                vwTll[idx] = llvw[(size_t)k * CLL + r];
            } else {
                int i2 = idx - SL;
                int r = i2 / CHH, k = i2 % CHH;
                vwThh[i2] = hvw[(size_t)k * CHH + r];
            }
        }
        return;
    }
    int C, ti, tj, sk, b2, KC;
    const bf16* X; float* G;
    if (blk < 1152) {
        C = CHH; sk = blk % 8; int tl = (blk / 8) % 9; b2 = blk / 72; KC = 2048;
        ti = tl / 3; tj = tl % 3;
        X = xhh + (size_t)b2 * CHH * NPIX; G = Ghh + (size_t)b2 * SH;
    } else {
        int j = blk - 1152;
        C = CLL; sk = j % 16; b2 = j / 16; KC = 1024; ti = 0; tj = 0;
        X = xll + (size_t)b2 * CLL * NPIX; G = Gll + (size_t)b2 * SL;
    }
    int lane = t & 63, wv = t >> 6;
    int g = lane >> 4, l15 = lane & 15;
    int rowi = t >> 3, chunk = t & 7;
    int k0 = sk * KC;
    const bf16* gA0 = X + (size_t)(ti * 64 + rowi) * NPIX + k0 + chunk * 8;
    const bf16* gA1 = gA0 + (size_t)32 * NPIX;
    const bf16* gB0 = X + (size_t)(tj * 64 + rowi) * NPIX + k0 + chunk * 8;
    const bf16* gB1 = gB0 + (size_t)32 * NPIX;
    int swc = (chunk ^ (rowi & 7)) * 8;
    bf16* lA0 = sA + rowi * 64 + swc;
    bf16* lA1 = sA + (rowi + 32) * 64 + swc;
    bf16* lB0 = sB + rowi * 64 + swc;
    bf16* lB1 = sB + (rowi + 32) * 64 + swc;
    int arow = (wv >> 1) * 32;
    int bcol = (wv & 1) * 32;
    int sw = l15 & 7;
    int roA0 = (arow + l15) * 64, roA1 = roA0 + 16 * 64;
    int roB0 = (bcol + l15) * 64, roB1 = roB0 + 16 * 64;
    f32x4 acc[2][2] = {};
    bf16x8 rA0 = *(const bf16x8*)gA0;
    bf16x8 rA1 = *(const bf16x8*)gA1;
    bf16x8 rB0 = *(const bf16x8*)gB0;
    bf16x8 rB1 = *(const bf16x8*)gB1;
    for (int kc = 0; kc < KC; kc += 64) {
        *(bf16x8*)lA0 = rA0; *(bf16x8*)lA1 = rA1;
        *(bf16x8*)lB0 = rB0; *(bf16x8*)lB1 = rB1;
        __syncthreads();
        if (kc + 64 < KC) {
            rA0 = *(const bf16x8*)(gA0 + kc + 64);
            rA1 = *(const bf16x8*)(gA1 + kc + 64);
            rB0 = *(const bf16x8*)(gB0 + kc + 64);
            rB1 = *(const bf16x8*)(gB1 + kc + 64);
        }
        #pragma unroll
        for (int ks = 0; ks < 2; ks++) {
            int ck = ((ks * 4 + g) ^ sw) * 8;
            bf16x8 a0 = *(const bf16x8*)(sA + roA0 + ck);
            bf16x8 a1 = *(const bf16x8*)(sA + roA1 + ck);
            bf16x8 b0 = *(const bf16x8*)(sB + roB0 + ck);
            bf16x8 b1 = *(const bf16x8*)(sB + roB1 + ck);
            acc[0][0] = __builtin_amdgcn_mfma_f32_16x16x32_bf16(a0, b0, acc[0][0], 0, 0, 0);
            acc[0][1] = __builtin_amdgcn_mfma_f32_16x16x32_bf16(a0, b1, acc[0][1], 0, 0, 0);
            acc[1][0] = __builtin_amdgcn_mfma_f32_16x16x32_bf16(a1, b0, acc[1][0], 0, 0, 0);
            acc[1][1] = __builtin_amdgcn_mfma_f32_16x16x32_bf16(a1, b1, acc[1][1], 0, 0, 0);
        }
        __syncthreads();
    }
    int r0q = ti * 64 + arow;
    int c0q = tj * 64 + bcol;
    #pragma unroll
    for (int rr = 0; rr < 2; rr++)
        #pragma unroll
        for (int c2 = 0; c2 < 2; c2++)
            #pragma unroll
            for (int rg = 0; rg < 4; rg++) {
                int row = r0q + rr * 16 + g * 4 + rg;
                int col = c0q + c2 * 16 + l15;
                atomicAdd(&G[(size_t)row * C + col], acc[rr][c2][rg]);
            }
}

// ---------------- unified NT-GEMM: out[r][c] = sum_k X[r][k]*Y[c][k] ------------------------
template <typename OUT>
__global__ __launch_bounds__(256) void k_ntu(
        const float* __restrict__ Xll0, const float* __restrict__ Xll1, long XllbS,
        const float* __restrict__ Yll, long YllbS,
        OUT* __restrict__ Oll, long OllzS, long OllbS,
        const float* __restrict__ Xhh0, const float* __restrict__ Xhh1, long XhhbS,
        const float* __restrict__ Yhh, long YhhbS,
        OUT* __restrict__ Ohh, long OhhzS, long OhhbS) {
    int x = blockIdx.x, b = blockIdx.y, z = blockIdx.z;
    int C, rt, ct;
    const float *X, *Y;
    OUT* O;
    if (x == 0) {
        C = CLL; rt = 0; ct = 0;
        X = (z ? Xll1 : Xll0) + (size_t)b * XllbS;
        Y = Yll + (size_t)b * YllbS;
        O = Oll + (size_t)z * OllzS + (size_t)b * OllbS;
    } else {
        C = CHH; int tl = x - 1; rt = tl / 3; ct = tl % 3;
        X = (z ? Xhh1 : Xhh0) + (size_t)b * XhhbS;
        Y = Yhh + (size_t)b * YhhbS;
        O = Ohh + (size_t)z * OhhzS + (size_t)b * OhhbS;
    }
    int t = threadIdx.x, ti = t >> 4, tj = t & 15;
    const float* xr = X + (size_t)(rt * 64 + ti * 4) * C;
    const float* yr = Y + (size_t)(ct * 64 + tj * 4) * C;
    float acc[4][4] = {};
    for (int k = 0; k < C; k += 4) {
        float4 xa[4], yb[4];
        #pragma unroll
        for (int a = 0; a < 4; a++) xa[a] = *(const float4*)(xr + (size_t)a * C + k);
        #pragma unroll
        for (int q = 0; q < 4; q++) yb[q] = *(const float4*)(yr + (size_t)q * C + k);
        #pragma unroll
        for (int a = 0; a < 4; a++)
            #pragma unroll
            for (int q = 0; q < 4; q++)
                acc[a][q] += xa[a].x * yb[q].x + xa[a].y * yb[q].y
                           + xa[a].z * yb[q].z + xa[a].w * yb[q].w;
    }
    #pragma unroll
    for (int a = 0; a < 4; a++) {
        int row = rt * 64 + ti * 4 + a, col = ct * 64 + tj * 4;
        if constexpr (sizeof(OUT) == 4) {
            *(float4*)((float*)O + (size_t)row * C + col) =
                make_float4(acc[a][0], acc[a][1], acc[a][2], acc[a][3]);
        } else {
            bf16x4 v;
            v[0] = (bf16)acc[a][0]; v[1] = (bf16)acc[a][1];
            v[2] = (bf16)acc[a][2]; v[3] = (bf16)acc[a][3];
            *(bf16x4*)((bf16*)O + (size_t)row * C + col) = v;
        }
    }
}

// ---------------- k_lnrm: blocks 0..159 L-GEMM; blocks 160..2207 one nrm wave-task ----------
__global__ __launch_bounds__(256) void k_lnrm(
        const float* __restrict__ PRll, const float* __restrict__ PRhh,
        const float* __restrict__ llqw, const float* __restrict__ llkw,
        const float* __restrict__ hqw,  const float* __restrict__ hkw,
        const float* __restrict__ llqb, const float* __restrict__ llkb,
        const float* __restrict__ hqb,  const float* __restrict__ hkb,
        const float* __restrict__ sll,  const float* __restrict__ shh,
        float* __restrict__ nrmll, float* __restrict__ nrmhh,
        float* __restrict__ wsll,  float* __restrict__ wshh,
        float* __restrict__ Lll, float* __restrict__ Lhh) {
    int blk = blockIdx.x, t = threadIdx.x;
    if (blk >= 160) {
        int wvv = t >> 6, lane = t & 63;
        int wt = (blk - 160) * 4 + wvv;      // 0..8191 exactly
        int z = wt >> 12, b2 = (wt >> 8) & 15, gr = wt & 255;
        int C, i; const float *P, *w, *wb, *s; float *nrm, *ws;
        if (gr < CLL) {
            C = CLL; i = gr;
            P = PRll + ((size_t)z * NB + b2) * SL;
            w = z ? llkw : llqw; wb = z ? llkb : llqb;
            s = sll + (size_t)b2 * CLL;
            nrm = nrmll + ((size_t)z * NB + b2) * CLL;
            ws  = wsll  + ((size_t)z * NB + b2) * CLL;
        } else {
            C = CHH; i = gr - CLL;
            P = PRhh + ((size_t)z * NB + b2) * SH;
            w = z ? hkw : hqw; wb = z ? hkb : hqb;
            s = shh + (size_t)b2 * CHH;
            nrm = nrmhh + ((size_t)z * NB + b2) * CHH;
            ws  = wshh  + ((size_t)z * NB + b2) * CHH;
        }
        const float* Pi = P + (size_t)i * C;
        const float* wi = w + (size_t)i * C;
        float np = 0.f, sd = 0.f;
        for (int j = lane; j < C; j += 64) {
            float wj = wi[j];
            np += Pi[j] * wj;
            sd += wj * s[j];
        }
        for (int o = 32; o; o >>= 1) { np += __shfl_down(np, o); sd += __shfl_down(sd, o); }
        if (lane == 0) {
            float wbi = wb[i];
            float q2 = np + 2.f * wbi * sd + (float)NPIX * wbi * wbi;
            nrm[i] = fmaxf(sqrtf(fmaxf(q2, 0.f)), 1e-12f);
            ws[i] = sd;
        }
        return;
    }
    // L GEMM (z=0 slab of PR, NT with kw)
    int x = blk % 10, b = blk / 10;
    int C, rt, ct;
    const float *X, *Y; float* O;
    if (x == 0) {
        C = CLL; rt = 0; ct = 0;
        X = PRll + (size_t)b * SL; Y = llkw; O = Lll + (size_t)b * SL;
    } else {
        C = CHH; int tl = x - 1; rt = tl / 3; ct = tl % 3;
        X = PRhh + (size_t)b * SH; Y = hkw; O = Lhh + (size_t)b * SH;
    }
    int ti = t >> 4, tj = t & 15;
    const float* xr = X + (size_t)(rt * 64 + ti * 4) * C;
    const float* yr = Y + (size_t)(ct * 64 + tj * 4) * C;
    float acc[4][4] = {};
    for (int k = 0; k < C; k += 4) {
        float4 xa[4], yb[4];
        #pragma unroll
        for (int a = 0; a < 4; a++) xa[a] = *(const float4*)(xr + (size_t)a * C + k);
        #pragma unroll
        for (int q = 0; q < 4; q++) yb[q] = *(const float4*)(yr + (size_t)q * C + k);
        #pragma unroll
        for (int a = 0; a < 4; a++)
            #pragma unroll
            for (int q = 0; q < 4; q++)
                acc[a][q] += xa[a].x * yb[q].x + xa[a].y * yb[q].y
                           + xa[a].z * yb[q].z + xa[a].w * yb[q].w;
    }
    #pragma unroll
    for (int a = 0; a < 4; a++) {
        int row = rt * 64 + ti * 4 + a, col = ct * 64 + tj * 4;
        *(float4*)(O + (size_t)row * C + col) =
            make_float4(acc[a][0], acc[a][1], acc[a][2], acc[a][3]);
    }
}

// ---------------- softmax (both branches, wave per row): logits -> A, av = A*vb --------------
__global__ __launch_bounds__(256) void k_soft2(
        const float* __restrict__ Lll, const float* __restrict__ Lhh,
        const float* __restrict__ llkb, const float* __restrict__ llqb,
        const float* __restrict__ hkb,  const float* __restrict__ hqb,
        const float* __restrict__ nrmll, const float* __restrict__ nrmhh,
        const float* __restrict__ wsll,  const float* __restrict__ wshh,
        const float* __restrict__ llvb,  const float* __restrict__ hvb,
        const float* __restrict__ lltp,  const float* __restrict__ htp,
        float* __restrict__ All, float* __restrict__ Ahh,
        float* __restrict__ avll, float* __restrict__ avhh) {
    int b = blockIdx.y;
    int wv = threadIdx.x >> 6, lane = threadIdx.x & 63;
    int gr = blockIdx.x * 4 + wv;   // 0..255
    int C, i; const float *Lb, *kb, *qb, *qn, *kn, *qs, *ks, *vb, *tp;
    float *A, *av;
    if (gr < CLL) {
        C = CLL; i = gr;
        Lb = Lll + (size_t)b * SL; kb = llkb; qb = llqb;
        qn = nrmll + (size_t)b * CLL;  kn = nrmll + ((size_t)NB + b) * CLL;
        qs = wsll + (size_t)b * CLL;   ks = wsll + ((size_t)NB + b) * CLL;
        vb = llvb; tp = lltp;
        A = All + (size_t)b * SL; av = avll + (size_t)b * CLL;
    } else {
        C = CHH; i = gr - CLL;
        Lb = Lhh + (size_t)b * SH; kb = hkb; qb = hqb;
        qn = nrmhh + (size_t)b * CHH;  kn = nrmhh + ((size_t)NB + b) * CHH;
        qs = wshh + (size_t)b * CHH;   ks = wshh + ((size_t)NB + b) * CHH;
        vb = hvb; tp = htp;
        A = Ahh + (size_t)b * SH; av = avhh + (size_t)b * CHH;
    }
    const float* Li = Lb + (size_t)i * C;
    float qni = qn[i], qsi = qs[i], qbi = qb[i], tmp = tp[0];
    float Lv[3];
    #pragma unroll
    for (int s2 = 0; s2 < 3; s2++) {
        int j = lane + s2 * 64;
        if (j < C) {
            float l = Li[j] + qsi * kb[j] + qbi * ks[j] + (float)NPIX * qbi * kb[j];
            Lv[s2] = l / (qni * kn[j]) * tmp;
        } else Lv[s2] = -1e30f;
    }
    float mx = fmaxf(fmaxf(Lv[0], Lv[1]), Lv[2]);
    for (int o = 32; o; o >>= 1) mx = fmaxf(mx, __shfl_xor(mx, o));
    float e[3], sum = 0.f;
    #pragma unroll
    for (int s2 = 0; s2 < 3; s2++) {
        e[s2] = (lane + s2 * 64 < C) ? expf(Lv[s2] - mx) : 0.f;
        sum += e[s2];
    }
    for (int o = 32; o; o >>= 1) sum += __shfl_xor(sum, o);
    float inv = 1.f / sum;
    float avp = 0.f;
    #pragma unroll
    for (int s2 = 0; s2 < 3; s2++) {
        int j = lane + s2 * 64;
        if (j < C) {
            float a = e[s2] * inv;
            A[(size_t)i * C + j] = a;
            avp += a * vb[j];
        }
    }
    for (int o = 32; o; o >>= 1) avp += __shfl_down(avp, o);
    if (lane == 0) av[i] = avp;
}

// ---------------- k_wtmv: blocks 0..159 WT-GEMM; blocks 160..1183 one mv wave-task ----------
__global__ __launch_bounds__(256) void k_wtmv(
        const float* __restrict__ vwTll, const float* __restrict__ vwThh,
        const float* __restrict__ All, const float* __restrict__ Ahh,
        const float* __restrict__ llpw, const float* __restrict__ llpb,
        const float* __restrict__ hpw,  const float* __restrict__ hpb,
        const float* __restrict__ avll, const float* __restrict__ avhh,
        float* __restrict__ WTll, float* __restrict__ WThh,
        float* __restrict__ mvll, float* __restrict__ mvhh) {
    int blk = blockIdx.x, t = threadIdx.x;
    if (blk >= 160) {
        int wvv = t >> 6, lane = t & 63;
        int wt = (blk - 160) * 4 + wvv;      // 0..4095 exactly
        int b2 = wt >> 8, gr = wt & 255;
        int C, i; const float *pw, *pb_, *av_; float* mv_;
        if (gr < CLL) {
            C = CLL; i = gr;
            pw = llpw; pb_ = llpb; av_ = avll + (size_t)b2 * CLL; mv_ = mvll + (size_t)b2 * CLL;
        } else {
            C = CHH; i = gr - CLL;
            pw = hpw; pb_ = hpb; av_ = avhh + (size_t)b2 * CHH; mv_ = mvhh + (size_t)b2 * CHH;
        }
        const float* pwi = pw + (size_t)i * C;
        float m = 0.f;
        for (int k = lane; k < C; k += 64) m += pwi[k] * av_[k];
        for (int o = 32; o; o >>= 1) m += __shfl_down(m, o);
        if (lane == 0) mv_[i] = m + pb_[i];
        return;
    }
    // WT GEMM
    int x = blk % 10, b = blk / 10;
    int C, rt, ct;
    const float *X, *Y; float* O;
    if (x == 0) {
        C = CLL; rt = 0; ct = 0;
        X = vwTll; Y = All + (size_t)b * SL; O = WTll + (size_t)b * SL;
    } else {
        C = CHH; int tl = x - 1; rt = tl / 3; ct = tl % 3;
        X = vwThh; Y = Ahh + (size_t)b * SH; O = WThh + (size_t)b * SH;
    }
    int ti = t >> 4, tj = t & 15;
    const float* xr = X + (size_t)(rt * 64 + ti * 4) * C;
    const float* yr = Y + (size_t)(ct * 64 + tj * 4) * C;
    float acc[4][4] = {};
    for (int k = 0; k < C; k += 4) {
        float4 xa[4], yb[4];
        #pragma unroll
        for (int a = 0; a < 4; a++) xa[a] = *(const float4*)(xr + (size_t)a * C + k);
        #pragma unroll
        for (int q = 0; q < 4; q++) yb[q] = *(const float4*)(yr + (size_t)q * C + k);
        #pragma unroll
        for (int a = 0; a < 4; a++)
            #pragma unroll
            for (int q = 0; q < 4; q++)
                acc[a][q] += xa[a].x * yb[q].x + xa[a].y * yb[q].y
                           + xa[a].z * yb[q].z + xa[a].w * yb[q].w;
    }
    #pragma unroll
    for (int a = 0; a < 4; a++) {
        int row = rt * 64 + ti * 4 + a, col = ct * 64 + tj * 4;
        *(float4*)(O + (size_t)row * C + col) =
            make_float4(acc[a][0], acc[a][1], acc[a][2], acc[a][3]);
    }
}

// ---------------- Final: Y = M*X + mv (ll & hh), fused IDWT, write out ----------------------
__global__ __launch_bounds__(256) void k_final(const bf16* __restrict__ xll, const bf16* __restrict__ xhh,
                        const bf16* __restrict__ Mll, const bf16* __restrict__ Mhh,
                        const float* __restrict__ mvll, const float* __restrict__ mvhh,
                        float* __restrict__ out) {
    __shared__ alignas(16) float smemf[256 * 65];        // 66,560 B
    bf16* sxl = (bf16*)smemf;                            // 64*64*2 = 8 KB
    bf16* sxh = (bf16*)smemf + 64 * 64;                  // 64*192*2 = 24 KB
    float* Y = smemf;                                    // [256 rows][65] after barrier
    int b = blockIdx.y, tile = blockIdx.x;
    int irow = tile >> 1, j0 = (tile & 1) << 6;
    int n0 = irow * 128 + j0;
    int t = threadIdx.x;
    const bf16* Xl = xll + (size_t)b * CLL * NPIX;
    const bf16* Xh = xhh + (size_t)b * CHH * NPIX;
    for (int task = t; task < 512; task += 256) {
        int d = task >> 3, q = task & 7;
        bf16x8 v = *(const bf16x8*)(Xl + (size_t)d * NPIX + n0 + q * 8);
        int cs = (((d >> 3) ^ q) << 3) | (d & 7);
        #pragma unroll
        for (int p = 0; p < 8; p++) sxl[(q * 8 + p) * 64 + cs] = v[p];
    }
    for (int task = t; task < 1536; task += 256) {
        int d = task >> 3, q = task & 7;
        bf16x8 v = *(const bf16x8*)(Xh + (size_t)d * NPIX + n0 + q * 8);
        int c = d >> 3;
        int cs = ((((c & ~7) | ((c & 7) ^ q))) << 3) | (d & 7);
        #pragma unroll
        for (int p = 0; p < 8; p++) sxh[(q * 8 + p) * 192 + cs] = v[p];
    }
    __syncthreads();
    int wv = t >> 6, lane = t & 63, g = lane >> 4, l15 = lane & 15;
    f32x4 accL[4] = {};
    {
        const bf16* M = Mll + (size_t)b * SL + (size_t)(wv * 16 + l15) * CLL;
        #pragma unroll
        for (int ks = 0; ks < 2; ks++) {
            bf16x8 af = *(const bf16x8*)(M + ks * 32 + g * 8);
            int cc = ks * 4 + g;
            #pragma unroll
            for (int c2 = 0; c2 < 4; c2++) {
                int pxr = c2 * 16 + l15;
                int csw = cc ^ ((pxr >> 3) & 7);
                bf16x8 bfrag = *(const bf16x8*)(sxl + pxr * 64 + csw * 8);
                accL[c2] = __builtin_amdgcn_mfma_f32_16x16x32_bf16(af, bfrag, accL[c2], 0, 0, 0);
            }
        }
    }
    f32x4 accH[3][4] = {};
    {
        const bf16* M = Mhh + (size_t)b * SH;
        #pragma unroll 2
        for (int kb = 0; kb < CHH; kb += 32) {
            bf16x8 af[3];
            #pragma unroll
            for (int r = 0; r < 3; r++)
                af[r] = *(const bf16x8*)(M + (size_t)(wv * 48 + r * 16 + l15) * CHH + kb + g * 8);
            #pragma unroll
            for (int c2 = 0; c2 < 4; c2++) {
                int pxr = c2 * 16 + l15;
                int cc = (kb >> 3) + g;
                int csw = (cc & ~7) | ((cc & 7) ^ ((pxr >> 3) & 7));
                bf16x8 bfrag = *(const bf16x8*)(sxh + pxr * 192 + csw * 8);
                #pragma unroll
                for (int r = 0; r < 3; r++)
                    accH[r][c2] = __builtin_amdgcn_mfma_f32_16x16x32_bf16(af[r], bfrag, accH[r][c2], 0, 0, 0);
            }
        }
    }
    __syncthreads();   // staging reads done; smem becomes Y (stride 65)
    #pragma unroll
    for (int c2 = 0; c2 < 4; c2++)
        #pragma unroll
        for (int rg = 0; rg < 4; rg++) {
            int rl = wv * 16 + g * 4 + rg;
            Y[rl * 65 + c2 * 16 + l15] = accL[c2][rg] + mvll[b * CLL + rl];
        }
    #pragma unroll
    for (int r = 0; r < 3; r++)
        #pragma unroll
        for (int c2 = 0; c2 < 4; c2++)
            #pragma unroll
            for (int rg = 0; rg < 4; rg++) {
                int rh = wv * 48 + r * 16 + g * 4 + rg;
                Y[(64 + rh) * 65 + c2 * 16 + l15] = accH[r][c2][rg] + mvhh[b * CHH + rh];
            }
    __syncthreads();
    int p = t & 63, cg = t >> 6;
    float* ob = out + ((size_t)b * CLL) * 65536;
    for (int it = 0; it < 16; it++) {
        int c = it * 4 + cg;
        float ll = Y[c * 65 + p];
        float h1 = Y[(64 + 3 * c + 0) * 65 + p];
        float h2 = Y[(64 + 3 * c + 1) * 65 + p];
        float h3 = Y[(64 + 3 * c + 2) * 65 + p];
        float a  = (ll + h1 + h2 + h3) * 0.5f;
        float bb = (ll - h1 + h2 - h3) * 0.5f;
        float cc = (ll + h1 - h2 - h3) * 0.5f;
        float d  = (ll - h1 - h2 + h3) * 0.5f;
        int jj = j0 + p;
        float2* o0 = (float2*)(ob + ((size_t)c * 256 + 2 * irow) * 256 + 2 * jj);
        float2* o1 = (float2*)(ob + ((size_t)c * 256 + 2 * irow + 1) * 256 + 2 * jj);
        *o0 = make_float2(a, bb);
        *o1 = make_float2(cc, d);
    }
}

extern "C" void kernel_launch(void* const* d_in, const int* in_sizes, int n_in,
                              void* d_out, int out_size, void* d_ws, size_t ws_size,
                              hipStream_t stream) {
    const float* img    = (const float*)d_in[0];
    const float* ll_qw = (const float*)d_in[1];  const float* h_qw = (const float*)d_in[2];
    const float* ll_qb = (const float*)d_in[3];  const float* h_qb = (const float*)d_in[4];
    const float* ll_kw = (const float*)d_in[5];  const float* h_kw = (const float*)d_in[6];
    const float* ll_kb = (const float*)d_in[7];  const float* h_kb = (const float*)d_in[8];
    const float* ll_vw = (const float*)d_in[9];  const float* h_vw = (const float*)d_in[10];
    const float* ll_vb = (const float*)d_in[11]; const float* h_vb = (const float*)d_in[12];
    const float* ll_pw = (const float*)d_in[13]; const float* h_pw = (const float*)d_in[14];
    const float* ll_pb = (const float*)d_in[15]; const float* h_pb = (const float*)d_in[16];
    const float* ll_tp = (const float*)d_in[17]; const float* h_tp = (const float*)d_in[18];
    float* out = (float*)d_out;

    char* ws = (char*)d_ws;
    size_t off = 0;
    auto alloc = [&](size_t sz) { char* p = ws + off; off += (sz + 255) & ~(size_t)255; return p; };
    bf16*  xll  = (bf16*) alloc((size_t)NB * CLL * NPIX * 2);
    bf16*  xhh  = (bf16*) alloc((size_t)NB * CHH * NPIX * 2);
    float* sll  = (float*)alloc(NB * CLL * 4);
    float* shh  = (float*)alloc(NB * CHH * 4);
    float* Gll  = (float*)alloc((size_t)NB * SL * 4);
    float* Ghh  = (float*)alloc((size_t)NB * SH * 4);
    float* PRll = (float*)alloc(2 * (size_t)NB * SL * 4);     // [z][b][C][C], z: 0=q,1=k
    float* PRhh = (float*)alloc(2 * (size_t)NB * SH * 4);
    float* nrmll= (float*)alloc(2 * NB * CLL * 4);    // [z][b][C]
    float* nrmhh= (float*)alloc(2 * NB * CHH * 4);
    float* wsll = (float*)alloc(2 * NB * CLL * 4);
    float* wshh = (float*)alloc(2 * NB * CHH * 4);
    float* Lll  = (float*)alloc((size_t)NB * SL * 4);
    float* Lhh  = (float*)alloc((size_t)NB * SH * 4);
    float* All  = (float*)alloc((size_t)NB * SL * 4);
    float* Ahh  = (float*)alloc((size_t)NB * SH * 4);
    float* avll = (float*)alloc(NB * CLL * 4);   float* avhh = (float*)alloc(NB * CHH * 4);
    float* WTll = (float*)alloc((size_t)NB * SL * 4);
    float* WThh = (float*)alloc((size_t)NB * SH * 4);
    float* vwTll= (float*)alloc(SL * 4);
    float* vwThh= (float*)alloc(SH * 4);
    bf16*  Mll  = (bf16*) alloc((size_t)NB * SL * 2);
    bf16*  Mhh  = (bf16*) alloc((size_t)NB * SH * 2);
    float* mvll = (float*)alloc(NB * CLL * 4);   float* mvhh = (float*)alloc(NB * CHH * 4);

    k_dwt<<<1024, 256, 0, stream>>>(img, xll, xhh, sll, shh, Gll, Ghh);

    // full-tile gram (no mirror needed) + vw^T transpose tail
    k_gramv<<<1440, 256, 0, stream>>>(xll, xhh, Gll, Ghh, ll_vw, h_vw, vwTll, vwThh);

    // P,R = {qw,kw} * G  (NT via G symmetry); z selects qw/kw
    k_ntu<float><<<dim3(10, NB, 2), 256, 0, stream>>>(
        ll_qw, ll_kw, 0, Gll, (long)SL, PRll, (long)NB * SL, (long)SL,
        h_qw,  h_kw,  0, Ghh, (long)SH, PRhh, (long)NB * SH, (long)SH);

    // L = P * kw^T (blocks 0..159) + nrm wave-tasks (blocks 160..2207)
    k_lnrm<<<2208, 256, 0, stream>>>(PRll, PRhh,
        ll_qw, ll_kw, h_qw, h_kw, ll_qb, ll_kb, h_qb, h_kb, sll, shh,
        nrmll, nrmhh, wsll, wshh, Lll, Lhh);

    k_soft2<<<dim3(64, NB), 256, 0, stream>>>(Lll, Lhh, ll_kb, ll_qb, h_kb, h_qb,
        nrmll, nrmhh, wsll, wshh, ll_vb, h_vb, ll_tp, h_tp, All, Ahh, avll, avhh);

    // WT = vw^T * A (blocks 0..159) + mv wave-tasks (blocks 160..1183)
    k_wtmv<<<1184, 256, 0, stream>>>(vwTll, vwThh, All, Ahh,
        ll_pw, ll_pb, h_pw, h_pb, avll, avhh, WTll, WThh, mvll, mvhh);

    // M = pw *NT* WT  (bf16 out)
    k_ntu<bf16><<<dim3(10, NB, 1), 256, 0, stream>>>(
        ll_pw, ll_pw, 0, WTll, (long)SL, Mll, 0, (long)SL,
        h_pw,  h_pw,  0, WThh, (long)SH, Mhh, 0, (long)SH);

    k_final<<<dim3(256, NB), 256, 0, stream>>>(xll, xhh, Mll, Mhh, mvll, mvhh, out);
}

// Round 15
// 403.287 us; speedup vs baseline: 1.0181x; 1.0181x over previous
//
#include <hip/hip_runtime.h>

typedef __bf16 bf16;
typedef bf16 bf16x8 __attribute__((ext_vector_type(8)));
typedef bf16 bf16x4 __attribute__((ext_vector_type(4)));
typedef float f32x4 __attribute__((ext_vector_type(4)));

#define NB 16
#define CLL 64
#define CHH 192
#define NPIX 16384
#define SL (CLL * CLL)
#define SH (CHH * CHH)

// ---------------- DWT: img(f32) -> X_ll, X_hh (bf16) + channel sums; also zeroes G ----------
// 1024 blocks, one per (b,c); 8 row-slabs per block; block-reduced sums (no atomics, no memset).
__global__ __launch_bounds__(256) void k_dwt(const float* __restrict__ img, bf16* __restrict__ xll,
                      bf16* __restrict__ xhh, float* __restrict__ sll, float* __restrict__ shh,
                      float* __restrict__ Gll, float* __restrict__ Ghh) {
    __shared__ float sred[4][4];
    int bc = blockIdx.x;           // b*64 + c
    int b = bc >> 6, c = bc & 63;
    int t = threadIdx.x;
    int q = t & 15;                        // 8-px col group
    // zero G slices (consumed by k_gramv next kernel; replay-safe)
    {
        float4 z4 = make_float4(0.f, 0.f, 0.f, 0.f);
        int gi = bc * 256 + t;
        if (gi < 16384)  ((float4*)Gll)[gi] = z4;    // 16384 float4 = NB*SL floats
        if (gi < 147456) ((float4*)Ghh)[gi] = z4;    // 147456 float4 = NB*SH floats
    }
    float s0 = 0.f, s1 = 0.f, s2 = 0.f, s3 = 0.f;
    for (int it = 0; it < 8; it++) {
        int r = it * 16 + (t >> 4);        // out row 0..127
        const float* p0 = img + ((size_t)bc << 16) + (size_t)(2 * r) * 256 + 16 * q;
        const float* p1 = p0 + 256;
        float4 e0[4], e1[4];
        #pragma unroll
        for (int l = 0; l < 4; l++) { e0[l] = ((const float4*)p0)[l]; e1[l] = ((const float4*)p1)[l]; }
        const float* f0 = (const float*)e0;
        const float* f1 = (const float*)e1;
        bf16x8 vll, v1, v2, v3;
        #pragma unroll
        for (int p = 0; p < 8; p++) {
            float a = f0[2 * p], bb = f0[2 * p + 1], cc = f1[2 * p], d = f1[2 * p + 1];
            float wll = (a + bb + cc + d) * 0.5f;
            float w1  = (a - bb + cc - d) * 0.5f;
            float w2  = (a + bb - cc - d) * 0.5f;
            float w3  = (a - bb - cc + d) * 0.5f;
            vll[p] = (bf16)wll; v1[p] = (bf16)w1; v2[p] = (bf16)w2; v3[p] = (bf16)w3;
            s0 += wll; s1 += w1; s2 += w2; s3 += w3;
        }
        size_t n = (size_t)r * 128 + 8 * q;
        *(bf16x8*)(xll + ((size_t)b * CLL + c) * NPIX + n) = vll;
        size_t hb = ((size_t)b * CHH + 3 * c) * NPIX + n;
        *(bf16x8*)(xhh + hb) = v1;
        *(bf16x8*)(xhh + hb + NPIX) = v2;
        *(bf16x8*)(xhh + hb + 2 * NPIX) = v3;
    }
    for (int o = 32; o; o >>= 1) {
        s0 += __shfl_down(s0, o); s1 += __shfl_down(s1, o);
        s2 += __shfl_down(s2, o); s3 += __shfl_down(s3, o);
    }
    int wv = t >> 6;
    if ((t & 63) == 0) {
        sred[wv][0] = s0; sred[wv][1] = s1; sred[wv][2] = s2; sred[wv][3] = s3;
    }
    __syncthreads();
    if (t == 0) {
        float r0 = sred[0][0] + sred[1][0] + sred[2][0] + sred[3][0];
        float r1 = sred[0][1] + sred[1][1] + sred[2][1] + sred[3][1];
        float r2 = sred[0][2] + sred[1][2] + sred[2][2] + sred[3][2];
        float r3 = sred[0][3] + sred[1][3] + sred[2][3] + sred[3][3];
        sll[b * CLL + c] = r0;
        shh[b * CHH + 3 * c + 0] = r1;
        shh[b * CHH + 3 * c + 1] = r2;
        shh[b * CHH + 3 * c + 2] = r3;
    }
}

// ---------------- gramv: unified gram (blocks 0..1023) + vw^T transpose (1024..1055) --------
__global__ __launch_bounds__(256) void k_gramv(const bf16* __restrict__ xll,
        const bf16* __restrict__ xhh, float* __restrict__ Gll, float* __restrict__ Ghh,
        const float* __restrict__ llvw, const float* __restrict__ hvw,
        float* __restrict__ vwTll, float* __restrict__ vwThh) {
    __shared__ bf16 sA[64 * 64];
    __shared__ bf16 sB[64 * 64];
    int blk = blockIdx.x, t = threadIdx.x;
    if (blk >= 1024) {                       // vw^T transpose tail
        int base = (blk - 1024) * 256 + t;
        for (int idx = base; idx < SL + SH; idx += 32 * 256) {
            if (idx < SL) {
                int r = idx / CLL, k = idx % CLL;
                vwTll[idx] = llvw[(size_t)k * CLL + r];
            } else {
                int i2 = idx - SL;
                int r = i2 / CHH, k = i2 % CHH;
                vwThh[i2] = hvw[(size_t)k * CHH + r];
            }
        }
        return;
    }
    int C, ti, tj, sk, b2, KC;
    const bf16* X; float* G;
    if (blk < 768) {
        C = CHH; sk = blk % 8; int tl = (blk / 8) % 6; b2 = blk / 48; KC = 2048;
        ti = (tl < 3) ? 0 : ((tl < 5) ? 1 : 2);
        tj = (tl < 3) ? tl : ((tl < 5) ? tl - 2 : 2);
        X = xhh + (size_t)b2 * CHH * NPIX; G = Ghh + (size_t)b2 * SH;
    } else {
        int j = blk - 768;
        C = CLL; sk = j % 16; b2 = j / 16; KC = 1024; ti = 0; tj = 0;
        X = xll + (size_t)b2 * CLL * NPIX; G = Gll + (size_t)b2 * SL;
    }
    int lane = t & 63, wv = t >> 6;
    int g = lane >> 4, l15 = lane & 15;
    int rowi = t >> 3, chunk = t & 7;
    int k0 = sk * KC;
    const bf16* gA0 = X + (size_t)(ti * 64 + rowi) * NPIX + k0 + chunk * 8;
    const bf16* gA1 = gA0 + (size_t)32 * NPIX;
    const bf16* gB0 = X + (size_t)(tj * 64 + rowi) * NPIX + k0 + chunk * 8;
    const bf16* gB1 = gB0 + (size_t)32 * NPIX;
    int swc = (chunk ^ (rowi & 7)) * 8;
    bf16* lA0 = sA + rowi * 64 + swc;
    bf16* lA1 = sA + (rowi + 32) * 64 + swc;
    bf16* lB0 = sB + rowi * 64 + swc;
    bf16* lB1 = sB + (rowi + 32) * 64 + swc;
    int arow = (wv >> 1) * 32;
    int bcol = (wv & 1) * 32;
    int sw = l15 & 7;
    int roA0 = (arow + l15) * 64, roA1 = roA0 + 16 * 64;
    int roB0 = (bcol + l15) * 64, roB1 = roB0 + 16 * 64;
    f32x4 acc[2][2] = {};
    bf16x8 rA0 = *(const bf16x8*)gA0;
    bf16x8 rA1 = *(const bf16x8*)gA1;
    bf16x8 rB0 = *(const bf16x8*)gB0;
    bf16x8 rB1 = *(const bf16x8*)gB1;
    for (int kc = 0; kc < KC; kc += 64) {
        *(bf16x8*)lA0 = rA0; *(bf16x8*)lA1 = rA1;
        *(bf16x8*)lB0 = rB0; *(bf16x8*)lB1 = rB1;
        __syncthreads();
        if (kc + 64 < KC) {
            rA0 = *(const bf16x8*)(gA0 + kc + 64);
            rA1 = *(const bf16x8*)(gA1 + kc + 64);
            rB0 = *(const bf16x8*)(gB0 + kc + 64);
            rB1 = *(const bf16x8*)(gB1 + kc + 64);
        }
        #pragma unroll
        for (int ks = 0; ks < 2; ks++) {
            int ck = ((ks * 4 + g) ^ sw) * 8;
            bf16x8 a0 = *(const bf16x8*)(sA + roA0 + ck);
            bf16x8 a1 = *(const bf16x8*)(sA + roA1 + ck);
            bf16x8 b0 = *(const bf16x8*)(sB + roB0 + ck);
            bf16x8 b1 = *(const bf16x8*)(sB + roB1 + ck);
            acc[0][0] = __builtin_amdgcn_mfma_f32_16x16x32_bf16(a0, b0, acc[0][0], 0, 0, 0);
            acc[0][1] = __builtin_amdgcn_mfma_f32_16x16x32_bf16(a0, b1, acc[0][1], 0, 0, 0);
            acc[1][0] = __builtin_amdgcn_mfma_f32_16x16x32_bf16(a1, b0, acc[1][0], 0, 0, 0);
            acc[1][1] = __builtin_amdgcn_mfma_f32_16x16x32_bf16(a1, b1, acc[1][1], 0, 0, 0);
        }
        __syncthreads();
    }
    int r0q = ti * 64 + arow;
    int c0q = tj * 64 + bcol;
    #pragma unroll
    for (int rr = 0; rr < 2; rr++)
        #pragma unroll
        for (int c2 = 0; c2 < 2; c2++)
            #pragma unroll
            for (int rg = 0; rg < 4; rg++) {
                int row = r0q + rr * 16 + g * 4 + rg;
                int col = c0q + c2 * 16 + l15;
                atomicAdd(&G[(size_t)row * C + col], acc[rr][c2][rg]);
            }
}

// ---------------- prep2: mirror G upper->lower (grid-stride) --------------------------------
__global__ void k_prep2(float* __restrict__ Gll, float* __restrict__ Ghh) {
    int total = NB * (SL + SH);
    for (int idx = blockIdx.x * 256 + threadIdx.x; idx < total; idx += gridDim.x * 256) {
        int b = idx / (SL + SH), r = idx % (SL + SH);
        if (r < SL) {
            float* Gb = Gll + (size_t)b * SL;
            int i = r / CLL, j = r % CLL;
            if (j < i) Gb[r] = Gb[(size_t)j * CLL + i];
        } else {
            int r2 = r - SL;
            float* Gb = Ghh + (size_t)b * SH;
            int i = r2 / CHH, j = r2 % CHH;
            if (j < i) Gb[r2] = Gb[(size_t)j * CHH + i];
        }
    }
}

// ---------------- unified NT-GEMM: out[r][c] = sum_k X[r][k]*Y[c][k] ------------------------
template <typename OUT>
__global__ __launch_bounds__(256) void k_ntu(
        const float* __restrict__ Xll0, const float* __restrict__ Xll1, long XllbS,
        const float* __restrict__ Yll, long YllbS,
        OUT* __restrict__ Oll, long OllzS, long OllbS,
        const float* __restrict__ Xhh0, const float* __restrict__ Xhh1, long XhhbS,
        const float* __restrict__ Yhh, long YhhbS,
        OUT* __restrict__ Ohh, long OhhzS, long OhhbS) {
    int x = blockIdx.x, b = blockIdx.y, z = blockIdx.z;
    int C, rt, ct;
    const float *X, *Y;
    OUT* O;
    if (x == 0) {
        C = CLL; rt = 0; ct = 0;
        X = (z ? Xll1 : Xll0) + (size_t)b * XllbS;
        Y = Yll + (size_t)b * YllbS;
        O = Oll + (size_t)z * OllzS + (size_t)b * OllbS;
    } else {
        C = CHH; int tl = x - 1; rt = tl / 3; ct = tl % 3;
        X = (z ? Xhh1 : Xhh0) + (size_t)b * XhhbS;
        Y = Yhh + (size_t)b * YhhbS;
        O = Ohh + (size_t)z * OhhzS + (size_t)b * OhhbS;
    }
    int t = threadIdx.x, ti = t >> 4, tj = t & 15;
    const float* xr = X + (size_t)(rt * 64 + ti * 4) * C;
    const float* yr = Y + (size_t)(ct * 64 + tj * 4) * C;
    float acc[4][4] = {};
    for (int k = 0; k < C; k += 4) {
        float4 xa[4], yb[4];
        #pragma unroll
        for (int a = 0; a < 4; a++) xa[a] = *(const float4*)(xr + (size_t)a * C + k);
        #pragma unroll
        for (int q = 0; q < 4; q++) yb[q] = *(const float4*)(yr + (size_t)q * C + k);
        #pragma unroll
        for (int a = 0; a < 4; a++)
            #pragma unroll
            for (int q = 0; q < 4; q++)
                acc[a][q] += xa[a].x * yb[q].x + xa[a].y * yb[q].y
                           + xa[a].z * yb[q].z + xa[a].w * yb[q].w;
    }
    #pragma unroll
    for (int a = 0; a < 4; a++) {
        int row = rt * 64 + ti * 4 + a, col = ct * 64 + tj * 4;
        if constexpr (sizeof(OUT) == 4) {
            *(float4*)((float*)O + (size_t)row * C + col) =
                make_float4(acc[a][0], acc[a][1], acc[a][2], acc[a][3]);
        } else {
            bf16x4 v;
            v[0] = (bf16)acc[a][0]; v[1] = (bf16)acc[a][1];
            v[2] = (bf16)acc[a][2]; v[3] = (bf16)acc[a][3];
            *(bf16x4*)((bf16*)O + (size_t)row * C + col) = v;
        }
    }
}

// ---------------- k_lnrm: blocks 0..159 L-GEMM; blocks 160..2207 one nrm wave-task ----------
__global__ __launch_bounds__(256) void k_lnrm(
        const float* __restrict__ PRll, const float* __restrict__ PRhh,
        const float* __restrict__ llqw, const float* __restrict__ llkw,
        const float* __restrict__ hqw,  const float* __restrict__ hkw,
        const float* __restrict__ llqb, const float* __restrict__ llkb,
        const float* __restrict__ hqb,  const float* __restrict__ hkb,
        const float* __restrict__ sll,  const float* __restrict__ shh,
        float* __restrict__ nrmll, float* __restrict__ nrmhh,
        float* __restrict__ wsll,  float* __restrict__ wshh,
        float* __restrict__ Lll, float* __restrict__ Lhh) {
    int blk = blockIdx.x, t = threadIdx.x;
    if (blk >= 160) {
        int wvv = t >> 6, lane = t & 63;
        int wt = (blk - 160) * 4 + wvv;      // 0..8191 exactly
        int z = wt >> 12, b2 = (wt >> 8) & 15, gr = wt & 255;
        int C, i; const float *P, *w, *wb, *s; float *nrm, *ws;
        if (gr < CLL) {
            C = CLL; i = gr;
            P = PRll + ((size_t)z * NB + b2) * SL;
            w = z ? llkw : llqw; wb = z ? llkb : llqb;
            s = sll + (size_t)b2 * CLL;
            nrm = nrmll + ((size_t)z * NB + b2) * CLL;
            ws  = wsll  + ((size_t)z * NB + b2) * CLL;
        } else {
            C = CHH; i = gr - CLL;
            P = PRhh + ((size_t)z * NB + b2) * SH;
            w = z ? hkw : hqw; wb = z ? hkb : hqb;
            s = shh + (size_t)b2 * CHH;
            nrm = nrmhh + ((size_t)z * NB + b2) * CHH;
            ws  = wshh  + ((size_t)z * NB + b2) * CHH;
        }
        const float* Pi = P + (size_t)i * C;
        const float* wi = w + (size_t)i * C;
        float np = 0.f, sd = 0.f;
        for (int j = lane; j < C; j += 64) {
            float wj = wi[j];
            np += Pi[j] * wj;
            sd += wj * s[j];
        }
        for (int o = 32; o; o >>= 1) { np += __shfl_down(np, o); sd += __shfl_down(sd, o); }
        if (lane == 0) {
            float wbi = wb[i];
            float q2 = np + 2.f * wbi * sd + (float)NPIX * wbi * wbi;
            nrm[i] = fmaxf(sqrtf(fmaxf(q2, 0.f)), 1e-12f);
            ws[i] = sd;
        }
        return;
    }
    // L GEMM (z=0 slab of PR, NT with kw)
    int x = blk % 10, b = blk / 10;
    int C, rt, ct;
    const float *X, *Y; float* O;
    if (x == 0) {
        C = CLL; rt = 0; ct = 0;
        X = PRll + (size_t)b * SL; Y = llkw; O = Lll + (size_t)b * SL;
    } else {
        C = CHH; int tl = x - 1; rt = tl / 3; ct = tl % 3;
        X = PRhh + (size_t)b * SH; Y = hkw; O = Lhh + (size_t)b * SH;
    }
    int ti = t >> 4, tj = t & 15;
    const float* xr = X + (size_t)(rt * 64 + ti * 4) * C;
    const float* yr = Y + (size_t)(ct * 64 + tj * 4) * C;
    float acc[4][4] = {};
    for (int k = 0; k < C; k += 4) {
        float4 xa[4], yb[4];
        #pragma unroll
        for (int a = 0; a < 4; a++) xa[a] = *(const float4*)(xr + (size_t)a * C + k);
        #pragma unroll
        for (int q = 0; q < 4; q++) yb[q] = *(const float4*)(yr + (size_t)q * C + k);
        #pragma unroll
        for (int a = 0; a < 4; a++)
            #pragma unroll
            for (int q = 0; q < 4; q++)
                acc[a][q] += xa[a].x * yb[q].x + xa[a].y * yb[q].y
                           + xa[a].z * yb[q].z + xa[a].w * yb[q].w;
    }
    #pragma unroll
    for (int a = 0; a < 4; a++) {
        int row = rt * 64 + ti * 4 + a, col = ct * 64 + tj * 4;
        *(float4*)(O + (size_t)row * C + col) =
            make_float4(acc[a][0], acc[a][1], acc[a][2], acc[a][3]);
    }
}

// ---------------- softmax (both branches, wave per row): logits -> A, av = A*vb --------------
__global__ __launch_bounds__(256) void k_soft2(
        const float* __restrict__ Lll, const float* __restrict__ Lhh,
        const float* __restrict__ llkb, const float* __restrict__ llqb,
        const float* __restrict__ hkb,  const float* __restrict__ hqb,
        const float* __restrict__ nrmll, const float* __restrict__ nrmhh,
        const float* __restrict__ wsll,  const float* __restrict__ wshh,
        const float* __restrict__ llvb,  const float* __restrict__ hvb,
        const float* __restrict__ lltp,  const float* __restrict__ htp,
        float* __restrict__ All, float* __restrict__ Ahh,
        float* __restrict__ avll, float* __restrict__ avhh) {
    int b = blockIdx.y;
    int wv = threadIdx.x >> 6, lane = threadIdx.x & 63;
    int gr = blockIdx.x * 4 + wv;   // 0..255
    int C, i; const float *Lb, *kb, *qb, *qn, *kn, *qs, *ks, *vb, *tp;
    float *A, *av;
    if (gr < CLL) {
        C = CLL; i = gr;
        Lb = Lll + (size_t)b * SL; kb = llkb; qb = llqb;
        qn = nrmll + (size_t)b * CLL;  kn = nrmll + ((size_t)NB + b) * CLL;
        qs = wsll + (size_t)b * CLL;   ks = wsll + ((size_t)NB + b) * CLL;
        vb = llvb; tp = lltp;
        A = All + (size_t)b * SL; av = avll + (size_t)b * CLL;
    } else {
        C = CHH; i = gr - CLL;
        Lb = Lhh + (size_t)b * SH; kb = hkb; qb = hqb;
        qn = nrmhh + (size_t)b * CHH;  kn = nrmhh + ((size_t)NB + b) * CHH;
        qs = wshh + (size_t)b * CHH;   ks = wshh + ((size_t)NB + b) * CHH;
        vb = hvb; tp = htp;
        A = Ahh + (size_t)b * SH; av = avhh + (size_t)b * CHH;
    }
    const float* Li = Lb + (size_t)i * C;
    float qni = qn[i], qsi = qs[i], qbi = qb[i], tmp = tp[0];
    float Lv[3];
    #pragma unroll
    for (int s2 = 0; s2 < 3; s2++) {
        int j = lane + s2 * 64;
        if (j < C) {
            float l = Li[j] + qsi * kb[j] + qbi * ks[j] + (float)NPIX * qbi * kb[j];
            Lv[s2] = l / (qni * kn[j]) * tmp;
        } else Lv[s2] = -1e30f;
    }
    float mx = fmaxf(fmaxf(Lv[0], Lv[1]), Lv[2]);
    for (int o = 32; o; o >>= 1) mx = fmaxf(mx, __shfl_xor(mx, o));
    float e[3], sum = 0.f;
    #pragma unroll
    for (int s2 = 0; s2 < 3; s2++) {
        e[s2] = (lane + s2 * 64 < C) ? expf(Lv[s2] - mx) : 0.f;
        sum += e[s2];
    }
    for (int o = 32; o; o >>= 1) sum += __shfl_xor(sum, o);
    float inv = 1.f / sum;
    float avp = 0.f;
    #pragma unroll
    for (int s2 = 0; s2 < 3; s2++) {
        int j = lane + s2 * 64;
        if (j < C) {
            float a = e[s2] * inv;
            A[(size_t)i * C + j] = a;
            avp += a * vb[j];
        }
    }
    for (int o = 32; o; o >>= 1) avp += __shfl_down(avp, o);
    if (lane == 0) av[i] = avp;
}

// ---------------- k_wtmv: blocks 0..159 WT-GEMM; blocks 160..1183 one mv wave-task ----------
__global__ __launch_bounds__(256) void k_wtmv(
        const float* __restrict__ vwTll, const float* __restrict__ vwThh,
        const float* __restrict__ All, const float* __restrict__ Ahh,
        const float* __restrict__ llpw, const float* __restrict__ llpb,
        const float* __restrict__ hpw,  const float* __restrict__ hpb,
        const float* __restrict__ avll, const float* __restrict__ avhh,
        float* __restrict__ WTll, float* __restrict__ WThh,
        float* __restrict__ mvll, float* __restrict__ mvhh) {
    int blk = blockIdx.x, t = threadIdx.x;
    if (blk >= 160) {
        int wvv = t >> 6, lane = t & 63;
        int wt = (blk - 160) * 4 + wvv;      // 0..4095 exactly
        int b2 = wt >> 8, gr = wt & 255;
        int C, i; const float *pw, *pb_, *av_; float* mv_;
        if (gr < CLL) {
            C = CLL; i = gr;
            pw = llpw; pb_ = llpb; av_ = avll + (size_t)b2 * CLL; mv_ = mvll + (size_t)b2 * CLL;
        } else {
            C = CHH; i = gr - CLL;
            pw = hpw; pb_ = hpb; av_ = avhh + (size_t)b2 * CHH; mv_ = mvhh + (size_t)b2 * CHH;
        }
        const float* pwi = pw + (size_t)i * C;
        float m = 0.f;
        for (int k = lane; k < C; k += 64) m += pwi[k] * av_[k];
        for (int o = 32; o; o >>= 1) m += __shfl_down(m, o);
        if (lane == 0) mv_[i] = m + pb_[i];
        return;
    }
    // WT GEMM
    int x = blk % 10, b = blk / 10;
    int C, rt, ct;
    const float *X, *Y; float* O;
    if (x == 0) {
        C = CLL; rt = 0; ct = 0;
        X = vwTll; Y = All + (size_t)b * SL; O = WTll + (size_t)b * SL;
    } else {
        C = CHH; int tl = x - 1; rt = tl / 3; ct = tl % 3;
        X = vwThh; Y = Ahh + (size_t)b * SH; O = WThh + (size_t)b * SH;
    }
    int ti = t >> 4, tj = t & 15;
    const float* xr = X + (size_t)(rt * 64 + ti * 4) * C;
    const float* yr = Y + (size_t)(ct * 64 + tj * 4) * C;
    float acc[4][4] = {};
    for (int k = 0; k < C; k += 4) {
        float4 xa[4], yb[4];
        #pragma unroll
        for (int a = 0; a < 4; a++) xa[a] = *(const float4*)(xr + (size_t)a * C + k);
        #pragma unroll
        for (int q = 0; q < 4; q++) yb[q] = *(const float4*)(yr + (size_t)q * C + k);
        #pragma unroll
        for (int a = 0; a < 4; a++)
            #pragma unroll
            for (int q = 0; q < 4; q++)
                acc[a][q] += xa[a].x * yb[q].x + xa[a].y * yb[q].y
                           + xa[a].z * yb[q].z + xa[a].w * yb[q].w;
    }
    #pragma unroll
    for (int a = 0; a < 4; a++) {
        int row = rt * 64 + ti * 4 + a, col = ct * 64 + tj * 4;
        *(float4*)(O + (size_t)row * C + col) =
            make_float4(acc[a][0], acc[a][1], acc[a][2], acc[a][3]);
    }
}

// ---------------- Final: Y = M*X + mv (ll & hh), fused IDWT, write out ----------------------
__global__ __launch_bounds__(256) void k_final(const bf16* __restrict__ xll, const bf16* __restrict__ xhh,
                        const bf16* __restrict__ Mll, const bf16* __restrict__ Mhh,
                        const float* __restrict__ mvll, const float* __restrict__ mvhh,
                        float* __restrict__ out) {
    __shared__ alignas(16) float smemf[256 * 65];        // 66,560 B
    bf16* sxl = (bf16*)smemf;                            // 64*64*2 = 8 KB
    bf16* sxh = (bf16*)smemf + 64 * 64;                  // 64*192*2 = 24 KB
    float* Y = smemf;                                    // [256 rows][65] after barrier
    int b = blockIdx.y, tile = blockIdx.x;
    int irow = tile >> 1, j0 = (tile & 1) << 6;
    int n0 = irow * 128 + j0;
    int t = threadIdx.x;
    const bf16* Xl = xll + (size_t)b * CLL * NPIX;
    const bf16* Xh = xhh + (size_t)b * CHH * NPIX;
    for (int task = t; task < 512; task += 256) {
        int d = task >> 3, q = task & 7;
        bf16x8 v = *(const bf16x8*)(Xl + (size_t)d * NPIX + n0 + q * 8);
        int cs = (((d >> 3) ^ q) << 3) | (d & 7);
        #pragma unroll
        for (int p = 0; p < 8; p++) sxl[(q * 8 + p) * 64 + cs] = v[p];
    }
    for (int task = t; task < 1536; task += 256) {
        int d = task >> 3, q = task & 7;
        bf16x8 v = *(const bf16x8*)(Xh + (size_t)d * NPIX + n0 + q * 8);
        int c = d >> 3;
        int cs = ((((c & ~7) | ((c & 7) ^ q))) << 3) | (d & 7);
        #pragma unroll
        for (int p = 0; p < 8; p++) sxh[(q * 8 + p) * 192 + cs] = v[p];
    }
    __syncthreads();
    int wv = t >> 6, lane = t & 63, g = lane >> 4, l15 = lane & 15;
    f32x4 accL[4] = {};
    {
        const bf16* M = Mll + (size_t)b * SL + (size_t)(wv * 16 + l15) * CLL;
        #pragma unroll
        for (int ks = 0; ks < 2; ks++) {
            bf16x8 af = *(const bf16x8*)(M + ks * 32 + g * 8);
            int cc = ks * 4 + g;
            #pragma unroll
            for (int c2 = 0; c2 < 4; c2++) {
                int pxr = c2 * 16 + l15;
                int csw = cc ^ ((pxr >> 3) & 7);
                bf16x8 bfrag = *(const bf16x8*)(sxl + pxr * 64 + csw * 8);
                accL[c2] = __builtin_amdgcn_mfma_f32_16x16x32_bf16(af, bfrag, accL[c2], 0, 0, 0);
            }
        }
    }
    f32x4 accH[3][4] = {};
    {
        const bf16* M = Mhh + (size_t)b * SH;
        #pragma unroll 2
        for (int kb = 0; kb < CHH; kb += 32) {
            bf16x8 af[3];
            #pragma unroll
            for (int r = 0; r < 3; r++)
                af[r] = *(const bf16x8*)(M + (size_t)(wv * 48 + r * 16 + l15) * CHH + kb + g * 8);
            #pragma unroll
            for (int c2 = 0; c2 < 4; c2++) {
                int pxr = c2 * 16 + l15;
                int cc = (kb >> 3) + g;
                int csw = (cc & ~7) | ((cc & 7) ^ ((pxr >> 3) & 7));
                bf16x8 bfrag = *(const bf16x8*)(sxh + pxr * 192 + csw * 8);
                #pragma unroll
                for (int r = 0; r < 3; r++)
                    accH[r][c2] = __builtin_amdgcn_mfma_f32_16x16x32_bf16(af[r], bfrag, accH[r][c2], 0, 0, 0);
            }
        }
    }
    __syncthreads();   // staging reads done; smem becomes Y (stride 65)
    #pragma unroll
    for (int c2 = 0; c2 < 4; c2++)
        #pragma unroll
        for (int rg = 0; rg < 4; rg++) {
            int rl = wv * 16 + g * 4 + rg;
            Y[rl * 65 + c2 * 16 + l15] = accL[c2][rg] + mvll[b * CLL + rl];
        }
    #pragma unroll
    for (int r = 0; r < 3; r++)
        #pragma unroll
        for (int c2 = 0; c2 < 4; c2++)
            #pragma unroll
            for (int rg = 0; rg < 4; rg++) {
                int rh = wv * 48 + r * 16 + g * 4 + rg;
                Y[(64 + rh) * 65 + c2 * 16 + l15] = accH[r][c2][rg] + mvhh[b * CHH + rh];
            }
    __syncthreads();
    int p = t & 63, cg = t >> 6;
    float* ob = out + ((size_t)b * CLL) * 65536;
    for (int it = 0; it < 16; it++) {
        int c = it * 4 + cg;
        float ll = Y[c * 65 + p];
        float h1 = Y[(64 + 3 * c + 0) * 65 + p];
        float h2 = Y[(64 + 3 * c + 1) * 65 + p];
        float h3 = Y[(64 + 3 * c + 2) * 65 + p];
        float a  = (ll + h1 + h2 + h3) * 0.5f;
        float bb = (ll - h1 + h2 - h3) * 0.5f;
        float cc = (ll + h1 - h2 - h3) * 0.5f;
        float d  = (ll - h1 - h2 + h3) * 0.5f;
        int jj = j0 + p;
        float2* o0 = (float2*)(ob + ((size_t)c * 256 + 2 * irow) * 256 + 2 * jj);
        float2* o1 = (float2*)(ob + ((size_t)c * 256 + 2 * irow + 1) * 256 + 2 * jj);
        *o0 = make_float2(a, bb);
        *o1 = make_float2(cc, d);
    }
}

extern "C" void kernel_launch(void* const* d_in, const int* in_sizes, int n_in,
                              void* d_out, int out_size, void* d_ws, size_t ws_size,
                              hipStream_t stream) {
    const float* img    = (const float*)d_in[0];
    const float* ll_qw = (const float*)d_in[1];  const float* h_qw = (const float*)d_in[2];
    const float* ll_qb = (const float*)d_in[3];  const float* h_qb = (const float*)d_in[4];
    const float* ll_kw = (const float*)d_in[5];  const float* h_kw = (const float*)d_in[6];
    const float* ll_kb = (const float*)d_in[7];  const float* h_kb = (const float*)d_in[8];
    const float* ll_vw = (const float*)d_in[9];  const float* h_vw = (const float*)d_in[10];
    const float* ll_vb = (const float*)d_in[11]; const float* h_vb = (const float*)d_in[12];
    const float* ll_pw = (const float*)d_in[13]; const float* h_pw = (const float*)d_in[14];
    const float* ll_pb = (const float*)d_in[15]; const float* h_pb = (const float*)d_in[16];
    const float* ll_tp = (const float*)d_in[17]; const float* h_tp = (const float*)d_in[18];
    float* out = (float*)d_out;

    char* ws = (char*)d_ws;
    size_t off = 0;
    auto alloc = [&](size_t sz) { char* p = ws + off; off += (sz + 255) & ~(size_t)255; return p; };
    bf16*  xll  = (bf16*) alloc((size_t)NB * CLL * NPIX * 2);
    bf16*  xhh  = (bf16*) alloc((size_t)NB * CHH * NPIX * 2);
    float* sll  = (float*)alloc(NB * CLL * 4);
    float* shh  = (float*)alloc(NB * CHH * 4);
    float* Gll  = (float*)alloc((size_t)NB * SL * 4);
    float* Ghh  = (float*)alloc((size_t)NB * SH * 4);
    float* PRll = (float*)alloc(2 * (size_t)NB * SL * 4);     // [z][b][C][C], z: 0=q,1=k
    float* PRhh = (float*)alloc(2 * (size_t)NB * SH * 4);
    float* nrmll= (float*)alloc(2 * NB * CLL * 4);    // [z][b][C]
    float* nrmhh= (float*)alloc(2 * NB * CHH * 4);
    float* wsll = (float*)alloc(2 * NB * CLL * 4);
    float* wshh = (float*)alloc(2 * NB * CHH * 4);
    float* Lll  = (float*)alloc((size_t)NB * SL * 4);
    float* Lhh  = (float*)alloc((size_t)NB * SH * 4);
    float* All  = (float*)alloc((size_t)NB * SL * 4);
    float* Ahh  = (float*)alloc((size_t)NB * SH * 4);
    float* avll = (float*)alloc(NB * CLL * 4);   float* avhh = (float*)alloc(NB * CHH * 4);
    float* WTll = (float*)alloc((size_t)NB * SL * 4);
    float* WThh = (float*)alloc((size_t)NB * SH * 4);
    float* vwTll= (float*)alloc(SL * 4);
    float* vwThh= (float*)alloc(SH * 4);
    bf16*  Mll  = (bf16*) alloc((size_t)NB * SL * 2);
    bf16*  Mhh  = (bf16*) alloc((size_t)NB * SH * 2);
    float* mvll = (float*)alloc(NB * CLL * 4);   float* mvhh = (float*)alloc(NB * CHH * 4);

    k_dwt<<<1024, 256, 0, stream>>>(img, xll, xhh, sll, shh, Gll, Ghh);

    k_gramv<<<1056, 256, 0, stream>>>(xll, xhh, Gll, Ghh, ll_vw, h_vw, vwTll, vwThh);

    k_prep2<<<1024, 256, 0, stream>>>(Gll, Ghh);

    // P,R = {qw,kw} * G  (NT via G symmetry); z selects qw/kw
    k_ntu<float><<<dim3(10, NB, 2), 256, 0, stream>>>(
        ll_qw, ll_kw, 0, Gll, (long)SL, PRll, (long)NB * SL, (long)SL,
        h_qw,  h_kw,  0, Ghh, (long)SH, PRhh, (long)NB * SH, (long)SH);

    // L = P * kw^T (blocks 0..159) + nrm wave-tasks (blocks 160..2207)
    k_lnrm<<<2208, 256, 0, stream>>>(PRll, PRhh,
        ll_qw, ll_kw, h_qw, h_kw, ll_qb, ll_kb, h_qb, h_kb, sll, shh,
        nrmll, nrmhh, wsll, wshh, Lll, Lhh);

    k_soft2<<<dim3(64, NB), 256, 0, stream>>>(Lll, Lhh, ll_kb, ll_qb, h_kb, h_qb,
        nrmll, nrmhh, wsll, wshh, ll_vb, h_vb, ll_tp, h_tp, All, Ahh, avll, avhh);

    // WT = vw^T * A (blocks 0..159) + mv wave-tasks (blocks 160..1183)
    k_wtmv<<<1184, 256, 0, stream>>>(vwTll, vwThh, All, Ahh,
        ll_pw, ll_pb, h_pw, h_pb, avll, avhh, WTll, WThh, mvll, mvhh);

    // M = pw *NT* WT  (bf16 out)
    k_ntu<bf16><<<dim3(10, NB, 1), 256, 0, stream>>>(
        ll_pw, ll_pw, 0, WTll, (long)SL, Mll, 0, (long)SL,
        h_pw,  h_pw,  0, WThh, (long)SH, Mhh, 0, (long)SH);

    k_final<<<dim3(256, NB), 256, 0, stream>>>(xll, xhh, Mll, Mhh, mvll, mvhh, out);
}